// Round 11
// baseline (214.264 us; speedup 1.0000x reference)
//
#include <hip/hip_runtime.h>
#include <math.h>

#define B_ 16
#define P_ 19248
#define C_ 81
#define O_ 32
#define POS_TH 0.5f
#define NEG_TH 0.4f
#define RPB 128              // rows per k_main block; B_*P_ = 307968 = 2406*128
#define TPB 512              // 8 waves x 16 rows/wave
#define PQ  4812             // P_/4: priors per best_prior quarter-block
#define BP_BLK (B_ * O_ * 4) // 2048 best_prior quarter blocks
#define BT_BPB 76            // ceil(P_/256) best_truth blocks per batch
#define NJ 38                // ceil(P_/512) per-thread elements in k_ohem

__device__ __forceinline__ float sl1(float x) {
    float d = fabsf(x);
    return (d < 1.0f) ? 0.5f * d * d : d - 0.5f;
}

__device__ __forceinline__ float iou_gt_prior(float4 t, float4 pr) {
    float px1 = pr.x - pr.z * 0.5f;
    float py1 = pr.y - pr.w * 0.5f;
    float px2 = pr.x + pr.z * 0.5f;
    float py2 = pr.y + pr.w * 0.5f;
    float ltx = fmaxf(t.x, px1), lty = fmaxf(t.y, py1);
    float rbx = fminf(t.z, px2), rby = fminf(t.w, py2);
    float iw = fmaxf(rbx - ltx, 0.0f), ih = fmaxf(rby - lty, 0.0f);
    float inter = iw * ih;
    float area_t = (t.z - t.x) * (t.w - t.y);
    float area_p = (px2 - px1) * (py2 - py1);
    return inter / (area_t + area_p - inter);
}

// ---- parallel threshold pick (512 threads, 8 waves) ----
template <int PER>
__device__ __forceinline__ void pick_top(const int* __restrict__ h, int kk, int tid,
                                         int* s_bin, int* s_kk, int* wsum) {
    const int lane = tid & 63, wid = tid >> 6;
    const int base = tid * PER;
    int v[PER]; int s = 0;
    #pragma unroll
    for (int j = 0; j < PER; ++j) { v[j] = h[base + j]; s += v[j]; }
    int x = s;                                  // inclusive suffix scan in wave
    #pragma unroll
    for (int d = 1; d < 64; d <<= 1) {
        int y = __shfl_down(x, d);
        if (lane + d < 64) x += y;
    }
    if (lane == 0) wsum[wid] = x;
    __syncthreads();
    int above = 0;
    #pragma unroll
    for (int w = 0; w < 8; ++w) if (w > wid) above += wsum[w];
    int T = (x - s) + above;
    if (T < kk && kk <= T + s) {                // exactly one thread true
        int kl = kk - T, cum = 0;
        #pragma unroll
        for (int j = PER - 1; j >= 0; --j) {
            if (cum + v[j] >= kl) { *s_bin = base + j; *s_kk = kl - cum; break; }
            cum += v[j];
        }
    }
    __syncthreads();
}

template <int PER>
__device__ __forceinline__ void pick_bot(const int* __restrict__ h, int kk, int tid,
                                         int* s_bin, int* s_kk, int* wsum) {
    const int lane = tid & 63, wid = tid >> 6;
    const int base = tid * PER;
    int v[PER]; int s = 0;
    #pragma unroll
    for (int j = 0; j < PER; ++j) { v[j] = h[base + j]; s += v[j]; }
    int x = s;                                  // inclusive prefix scan in wave
    #pragma unroll
    for (int d = 1; d < 64; d <<= 1) {
        int y = __shfl_up(x, d);
        if (lane >= d) x += y;
    }
    if (lane == 63) wsum[wid] = x;
    __syncthreads();
    int below = 0;
    #pragma unroll
    for (int w = 0; w < 8; ++w) if (w < wid) below += wsum[w];
    int T = (x - s) + below;
    if (T < kk && kk <= T + s) {
        int kl = kk - T, cum = 0;
        #pragma unroll
        for (int j = 0; j < PER; ++j) {
            if (cum + v[j] >= kl) { *s_bin = base + j; *s_kk = kl - cum; break; }
            cum += v[j];
        }
    }
    __syncthreads();
}

// Merged matcher (R10-verified).
__global__ void k_match(const float* __restrict__ priors,
                        const float* __restrict__ gt_boxes,
                        const int* __restrict__ gt_labels,
                        unsigned long long* __restrict__ best_key,
                        float* __restrict__ bt_ov,
                        int* __restrict__ bt_ix,
                        int* __restrict__ bt_lab) {
    const int bid = blockIdx.x;
    if (bid < BP_BLK) {
        int pair = bid >> 2, qtr = bid & 3;
        int b = pair >> 5, o = pair & 31;
        float4 t = ((const float4*)gt_boxes)[b * O_ + o];
        float bestv = -1.0f; int besti = 0;
        int pstart = qtr * PQ;
        for (int p = pstart + threadIdx.x; p < pstart + PQ; p += 256) {
            float4 pr = ((const float4*)priors)[p];
            float v = iou_gt_prior(t, pr);
            if (v > bestv) { bestv = v; besti = p; }
        }
        __shared__ float sv[256];
        __shared__ int   si[256];
        sv[threadIdx.x] = bestv; si[threadIdx.x] = besti;
        __syncthreads();
        for (int s = 128; s > 0; s >>= 1) {
            if (threadIdx.x < s) {
                float ov = sv[threadIdx.x + s]; int oi = si[threadIdx.x + s];
                if (ov > sv[threadIdx.x] ||
                    (ov == sv[threadIdx.x] && oi < si[threadIdx.x])) {
                    sv[threadIdx.x] = ov; si[threadIdx.x] = oi;
                }
            }
            __syncthreads();
        }
        if (threadIdx.x == 0) {
            unsigned long long key =
                ((unsigned long long)__float_as_uint(sv[0]) << 32) |
                (unsigned long long)(0xFFFFFFFFu - (unsigned int)si[0]);
            atomicMax(&best_key[pair], key);
        }
    } else {
        int idx = bid - BP_BLK;
        int b = idx / BT_BPB;
        int p = (idx % BT_BPB) * 256 + threadIdx.x;
        __shared__ float4 gt[O_];
        __shared__ int    gl[O_];
        if (threadIdx.x < O_) {
            gt[threadIdx.x] = ((const float4*)gt_boxes)[b * O_ + threadIdx.x];
            gl[threadIdx.x] = gt_labels[b * O_ + threadIdx.x];
        }
        __syncthreads();
        if (p >= P_) return;
        float4 pr = ((const float4*)priors)[p];
        float bestv = -1.0f; int besti = 0;
        for (int o = 0; o < O_; ++o) {
            float v = iou_gt_prior(gt[o], pr);
            if (v > bestv) { bestv = v; besti = o; }
        }
        size_t bp = (size_t)b * P_ + p;
        bt_ov[bp] = bestv;
        bt_ix[bp] = besti;
        bt_lab[bp] = gl[besti];
    }
}

// Force-match (numpy last-wins scatter) + zero downstream accumulators.
__global__ void k_force(const unsigned long long* __restrict__ best_key,
                        const int* __restrict__ gt_labels,
                        float* __restrict__ bt_ov,
                        int* __restrict__ bt_ix,
                        int* __restrict__ bt_lab,
                        int* __restrict__ num_pos,
                        float* __restrict__ accum,
                        int* __restrict__ done) {
    const int tid = threadIdx.x;          // 512 = 16 batches x 32 gts
    const int b = tid >> 5, o = tid & 31;
    unsigned long long key = best_key[b * O_ + o];
    int p  = (int)(0xFFFFFFFFu - (unsigned int)(key & 0xFFFFFFFFu));
    int ll = gt_labels[b * O_ + o];
    if (tid < B_) num_pos[tid] = 0;
    if (tid == 0) { accum[0] = 0.0f; accum[1] = 0.0f; *done = 0; }
    const int lanebase = tid & 32;        // batch's base lane within the wave
    for (int oo = 0; oo < O_; ++oo) {
        int pp = __shfl(p, lanebase + oo);
        int l2 = __shfl(ll, lanebase + oo);
        if (o == 0) {
            size_t idx = (size_t)b * P_ + pp;
            bt_ov[idx] = 2.0f;
            bt_ix[idx] = oo;
            bt_lab[idx] = l2;
        }
    }
}

// Main pass, wave-local pipeline: each wave stages ITS OWN 16 rows (5184B of
// the block's LDS) and computes on them with NO stage/compute barrier --
// waves pipeline independently, so some waves issue loads while others
// compute (R10's block-wide __syncthreads convoy was the stall: all waves
// staged, drained vmcnt(0), then all computed with memory idle).
// Block reduction via per-wave shfl + LDS slots + single END barrier.
__global__ __launch_bounds__(TPB) void
k_main(const float* __restrict__ loc_data,
       const float* __restrict__ conf_data,
       const float* __restrict__ priors,
       const float* __restrict__ gt_boxes,
       const float* __restrict__ bt_ov,
       const int* __restrict__ bt_ix,
       const int* __restrict__ bt_lab,
       float* __restrict__ lossc,
       float* __restrict__ ce_neg,
       int* __restrict__ num_pos,
       float* __restrict__ accum) {
    __shared__ float srow[RPB * C_];      // 41472 B; wave w owns [w*1296, +1296)
    __shared__ float s_part[8][2];
    const int tid = threadIdx.x;
    const int w = tid >> 6;               // wave id
    const int lane = tid & 63;
    const int tile = blockIdx.x;

    // ---- wave-local stage: 324 float4 for this wave's 16 rows ----
    {
        const float4* src = (const float4*)conf_data + (size_t)tile * 2592 + w * 324;
        float4* dst = (float4*)srow + w * 324;
        float4 t0 = src[lane];
        float4 t1 = src[lane + 64];
        float4 t2 = src[lane + 128];
        float4 t3 = src[lane + 192];
        float4 t4 = src[lane + 256];
        float4 t5;
        if (lane < 4) t5 = src[lane + 320];
        dst[lane]       = t0;
        dst[lane + 64]  = t1;
        dst[lane + 128] = t2;
        dst[lane + 192] = t3;
        dst[lane + 256] = t4;
        if (lane < 4) dst[lane + 320] = t5;
    }
    // no __syncthreads: wave reads only its own segment (lgkmcnt-ordered)

    const int r16 = lane >> 2;            // row within wave
    const int q = lane & 3;               // sub-row worker
    const int bp = tile * RPB + w * 16 + r16;
    const int b = bp / P_;
    const int bw0 = (tile * RPB + w * 16) / P_;   // wave's first-row batch
    const int p = bp - b * P_;
    const float* row = srow + (w * 16 + r16) * C_;
    const int j0 = 20 * q;

    float ma = row[j0], mb = row[j0 + 1], mc = row[j0 + 2], md = row[j0 + 3];
    #pragma unroll
    for (int i = 4; i < 20; i += 4) {
        ma = fmaxf(ma, row[j0 + i]);     mb = fmaxf(mb, row[j0 + i + 1]);
        mc = fmaxf(mc, row[j0 + i + 2]); md = fmaxf(md, row[j0 + i + 3]);
    }
    float m = fmaxf(fmaxf(ma, mb), fmaxf(mc, md));
    if (q == 3) m = fmaxf(m, row[80]);
    m = fmaxf(m, __shfl_xor(m, 1));
    m = fmaxf(m, __shfl_xor(m, 2));

    float sa = 0.f, sb = 0.f, sc = 0.f, sd = 0.f;
    #pragma unroll
    for (int i = 0; i < 20; i += 4) {
        sa += __expf(row[j0 + i] - m);     sb += __expf(row[j0 + i + 1] - m);
        sc += __expf(row[j0 + i + 2] - m); sd += __expf(row[j0 + i + 3] - m);
    }
    float s = (sa + sb) + (sc + sd);
    if (q == 3) s += __expf(row[80] - m);
    s += __shfl_xor(s, 1);
    s += __shfl_xor(s, 2);
    float logZ = m + __logf(s);

    // classification: only q==0 lanes load metadata; others default to bg
    float ov = 0.0f; int lab = -1;
    if (q == 0) { ov = bt_ov[bp]; lab = bt_lab[bp]; }
    int conf_t = lab + 1;
    if (ov < POS_TH) conf_t = -1;
    if (ov < NEG_TH) conf_t = 0;
    bool pos = (q == 0) && (conf_t > 0);

    float a0 = 0.0f, a1 = 0.0f;           // block-loss contributions
    if (q == 0) {
        float lc = (pos || conf_t < 0) ? 0.0f : (logZ - row[0]);
        int cls = pos ? conf_t : 0;
        float ce = logZ - row[cls];
        lossc[bp] = lc;
        ce_neg[bp] = (conf_t == 0) ? ce : 0.0f;
        if (pos) {
            int ti = bt_ix[bp];
            float4 t = ((const float4*)gt_boxes)[b * O_ + ti];
            float4 pr = ((const float4*)priors)[p];
            float mcx = (t.x + t.z) * 0.5f;
            float mcy = (t.y + t.w) * 0.5f;
            float gx = (mcx - pr.x) / (0.1f * pr.z);
            float gy = (mcy - pr.y) / (0.1f * pr.w);
            float gw = logf((t.z - t.x) / pr.z) / 0.2f;
            float gh = logf((t.w - t.y) / pr.w) / 0.2f;
            float4 ld = ((const float4*)loc_data)[bp];
            a0 = sl1(ld.x - gx) + sl1(ld.y - gy) + sl1(ld.z - gw) + sl1(ld.w - gh);
            a1 = ce;
        }
    }

    // per-wave num_pos via ballots (exact at batch boundary: <=2 batches/wave)
    unsigned long long bal0 = __ballot(pos && (b == bw0));
    unsigned long long bal1 = __ballot(pos && (b != bw0));
    if (lane == 0) {
        int c0 = (int)__popcll(bal0), c1 = (int)__popcll(bal1);
        if (c0) atomicAdd(&num_pos[bw0], c0);
        if (c1) atomicAdd(&num_pos[bw0 + 1], c1);
    }

    // per-wave shfl reduction of loss contributions -> LDS slot
    #pragma unroll
    for (int d = 1; d < 64; d <<= 1) {
        a0 += __shfl_xor(a0, d);
        a1 += __shfl_xor(a1, d);
    }
    if (lane == 0) { s_part[w][0] = a0; s_part[w][1] = a1; }
    __syncthreads();                      // END barrier only
    if (tid == 0) {
        float A = 0.0f, Bc = 0.0f;
        #pragma unroll
        for (int w2 = 0; w2 < 8; ++w2) { A += s_part[w2][0]; Bc += s_part[w2][1]; }
        if (A != 0.0f)  atomicAdd(&accum[0], A);
        if (Bc != 0.0f) atomicAdd(&accum[1], Bc);
    }
}

// One block per batch: register-cached radix select (exact stable-argsort
// semantics); last block folds the final scalars and writes out[2].
__global__ __launch_bounds__(512) void
k_ohem(const float* __restrict__ lossc, const float* __restrict__ ce_neg,
       const int* __restrict__ num_pos, const float* __restrict__ accum,
       float* __restrict__ ce_sum, int* __restrict__ done,
       float* __restrict__ out) {
    const int b = blockIdx.x;
    const int tid = threadIdx.x;
    const float* lc = lossc + (size_t)b * P_;
    const float* cn = ce_neg + (size_t)b * P_;
    __shared__ int h[2048];
    __shared__ int wsum[8];
    __shared__ int s_bin, s_kk;
    __shared__ float red[512];

    int k = 3 * num_pos[b];
    if (k > P_ - 1) k = P_ - 1;

    float result = 0.0f;
    if (k > 0) {
        unsigned int fb[NJ]; float cv[NJ];
        #pragma unroll
        for (int j = 0; j < NJ; ++j) {
            int i = tid + j * 512;
            bool valid = (i < P_);
            fb[j] = valid ? __float_as_uint(lc[i]) : 0xFFFFFFFFu;
            cv[j] = valid ? cn[i] : 0.0f;
        }
        // round 0: 1024-bin hist of fb>>21 (monotone, lossc >= 0)
        for (int i = tid; i < 2048; i += 512) h[i] = 0;
        __syncthreads();
        #pragma unroll
        for (int j = 0; j < NJ; ++j) atomicAdd(&h[fb[j] >> 21], 1);
        __syncthreads();
        pick_top<2>(h, k, tid, &s_bin, &s_kk, wsum);
        const unsigned int T = (unsigned int)s_bin;
        int kk = s_kk;

        // pass A: sum ce for bins > T; hist bits 20..10 of bin==T
        for (int i = tid; i < 2048; i += 512) h[i] = 0;
        __syncthreads();
        float sum = 0.0f;
        #pragma unroll
        for (int j = 0; j < NJ; ++j) {
            unsigned int bin = fb[j] >> 21;
            if (bin > T) sum += cv[j];                 // sentinel adds 0
            else if (bin == T) atomicAdd(&h[(fb[j] >> 10) & 2047], 1);
        }
        __syncthreads();
        pick_top<4>(h, kk, tid, &s_bin, &s_kk, wsum);
        const unsigned int pre21 = (T << 11) | (unsigned int)s_bin;
        kk = s_kk;

        // pass B: hist bits 9..0 of elements matching top 22 bits
        for (int i = tid; i < 1024; i += 512) h[i] = 0;
        __syncthreads();
        #pragma unroll
        for (int j = 0; j < NJ; ++j)
            if ((fb[j] >> 10) == pre21) atomicAdd(&h[fb[j] & 1023], 1);
        __syncthreads();
        pick_top<2>(h, kk, tid, &s_bin, &s_kk, wsum);
        const unsigned int V = (pre21 << 10) | (unsigned int)s_bin;
        const int ee = h[s_bin];
        kk = s_kk;

        if (kk == ee) {
            #pragma unroll
            for (int j = 0; j < NJ; ++j)
                if ((fb[j] >> 21) == T && fb[j] >= V) sum += cv[j];
        } else {
            // kk smallest-index elements with fb == V (stable argsort ties)
            for (int i = tid; i < 512; i += 512) h[i] = 0;
            __syncthreads();
            #pragma unroll
            for (int j = 0; j < NJ; ++j)
                if (fb[j] == V) atomicAdd(&h[(tid + j * 512) >> 6], 1);
            __syncthreads();
            pick_bot<1>(h, kk, tid, &s_bin, &s_kk, wsum);
            const int d6 = s_bin;
            kk = s_kk;
            h[tid] = 0;
            __syncthreads();
            #pragma unroll
            for (int j = 0; j < NJ; ++j) {
                int i = tid + j * 512;
                if (fb[j] == V && (i >> 6) == d6) atomicAdd(&h[i & 63], 1);
            }
            __syncthreads();
            pick_bot<1>(h, kk, tid, &s_bin, &s_kk, wsum);
            const int Istar = (d6 << 6) | s_bin;
            #pragma unroll
            for (int j = 0; j < NJ; ++j) {
                int i = tid + j * 512;
                if ((fb[j] >> 21) == T && (fb[j] > V || (fb[j] == V && i <= Istar)))
                    sum += cv[j];
            }
        }

        red[tid] = sum;
        __syncthreads();
        for (int s = 256; s > 0; s >>= 1) {
            if (tid < s) red[tid] += red[tid + s];
            __syncthreads();
        }
        result = red[0];
    }

    if (tid == 0) {
        ce_sum[b] = result;
        __threadfence();
        int old = atomicAdd(done, 1);
        if (old == B_ - 1) {                  // last block folds the output
            __threadfence();
            int tp = 0; float ns = 0.0f;
            for (int bb = 0; bb < B_; ++bb) { tp += num_pos[bb]; ns += ce_sum[bb]; }
            float inv = 1.0f / (float)tp;
            out[0] = accum[0] * 1.5f * inv;   // BBOX_ALPHA
            out[1] = (accum[1] + ns) * inv;   // CONF_ALPHA
        }
    }
}

extern "C" void kernel_launch(void* const* d_in, const int* in_sizes, int n_in,
                              void* d_out, int out_size, void* d_ws, size_t ws_size,
                              hipStream_t stream) {
    const float* loc    = (const float*)d_in[0];
    const float* conf   = (const float*)d_in[1];
    const float* priors = (const float*)d_in[2];
    const float* gtb    = (const float*)d_in[3];
    const int*   gtl    = (const int*)d_in[4];
    float* out = (float*)d_out;

    const size_t BP = (size_t)B_ * P_;
    float* W = (float*)d_ws;
    float* bt_ov   = W;
    float* lossc   = W + BP;
    float* ce_neg  = W + 2 * BP;
    int*   bt_ix   = (int*)(W + 3 * BP);
    int*   bt_lab  = (int*)(W + 4 * BP);
    unsigned long long* best_key = (unsigned long long*)(W + 5 * BP);  // 8B-aligned
    int*   num_pos = (int*)(best_key + B_ * O_);
    float* ce_sum  = (float*)(num_pos + B_);
    float* accum   = ce_sum + B_;
    int*   done    = (int*)(accum + 2);

    hipMemsetAsync(best_key, 0, B_ * O_ * sizeof(unsigned long long), stream);
    hipLaunchKernelGGL(k_match, dim3(BP_BLK + B_ * BT_BPB), dim3(256), 0, stream,
                       priors, gtb, gtl, best_key, bt_ov, bt_ix, bt_lab);
    hipLaunchKernelGGL(k_force, dim3(1), dim3(512), 0, stream,
                       best_key, gtl, bt_ov, bt_ix, bt_lab, num_pos, accum, done);
    hipLaunchKernelGGL(k_main, dim3((int)(BP / RPB)), dim3(TPB), 0, stream,
                       loc, conf, priors, gtb, bt_ov, bt_ix, bt_lab,
                       lossc, ce_neg, num_pos, accum);
    hipLaunchKernelGGL(k_ohem, dim3(B_), dim3(512), 0, stream,
                       lossc, ce_neg, num_pos, accum, ce_sum, done, out);
}

// Round 12
// 119.943 us; speedup vs baseline: 1.7864x; 1.7864x over previous
//
#include <hip/hip_runtime.h>
#include <math.h>

#define B_ 16
#define P_ 19248
#define C_ 81
#define O_ 32
#define POS_TH 0.5f
#define NEG_TH 0.4f
#define RPB 128              // rows per k_main tile; B_*P_ = 307968 = 2406*128
#define TPB 512              // threads per k_main block (8 waves), 4 threads/row
#define PQ  4812             // P_/4: priors per best_prior quarter-block
#define BP_BLK (B_ * O_ * 4) // 2048 best_prior quarter blocks
#define BT_BPB 76            // ceil(P_/256) best_truth blocks per batch
#define NJ 38                // ceil(P_/512) per-thread elements in k_ohem

__device__ __forceinline__ float sl1(float x) {
    float d = fabsf(x);
    return (d < 1.0f) ? 0.5f * d * d : d - 0.5f;
}

__device__ __forceinline__ float iou_gt_prior(float4 t, float4 pr) {
    float px1 = pr.x - pr.z * 0.5f;
    float py1 = pr.y - pr.w * 0.5f;
    float px2 = pr.x + pr.z * 0.5f;
    float py2 = pr.y + pr.w * 0.5f;
    float ltx = fmaxf(t.x, px1), lty = fmaxf(t.y, py1);
    float rbx = fminf(t.z, px2), rby = fminf(t.w, py2);
    float iw = fmaxf(rbx - ltx, 0.0f), ih = fmaxf(rby - lty, 0.0f);
    float inter = iw * ih;
    float area_t = (t.z - t.x) * (t.w - t.y);
    float area_p = (px2 - px1) * (py2 - py1);
    return inter / (area_t + area_p - inter);
}

// ---- parallel threshold pick (512 threads, 8 waves) ----
template <int PER>
__device__ __forceinline__ void pick_top(const int* __restrict__ h, int kk, int tid,
                                         int* s_bin, int* s_kk, int* wsum) {
    const int lane = tid & 63, wid = tid >> 6;
    const int base = tid * PER;
    int v[PER]; int s = 0;
    #pragma unroll
    for (int j = 0; j < PER; ++j) { v[j] = h[base + j]; s += v[j]; }
    int x = s;                                  // inclusive suffix scan in wave
    #pragma unroll
    for (int d = 1; d < 64; d <<= 1) {
        int y = __shfl_down(x, d);
        if (lane + d < 64) x += y;
    }
    if (lane == 0) wsum[wid] = x;
    __syncthreads();
    int above = 0;
    #pragma unroll
    for (int w = 0; w < 8; ++w) if (w > wid) above += wsum[w];
    int T = (x - s) + above;
    if (T < kk && kk <= T + s) {                // exactly one thread true
        int kl = kk - T, cum = 0;
        #pragma unroll
        for (int j = PER - 1; j >= 0; --j) {
            if (cum + v[j] >= kl) { *s_bin = base + j; *s_kk = kl - cum; break; }
            cum += v[j];
        }
    }
    __syncthreads();
}

template <int PER>
__device__ __forceinline__ void pick_bot(const int* __restrict__ h, int kk, int tid,
                                         int* s_bin, int* s_kk, int* wsum) {
    const int lane = tid & 63, wid = tid >> 6;
    const int base = tid * PER;
    int v[PER]; int s = 0;
    #pragma unroll
    for (int j = 0; j < PER; ++j) { v[j] = h[base + j]; s += v[j]; }
    int x = s;                                  // inclusive prefix scan in wave
    #pragma unroll
    for (int d = 1; d < 64; d <<= 1) {
        int y = __shfl_up(x, d);
        if (lane >= d) x += y;
    }
    if (lane == 63) wsum[wid] = x;
    __syncthreads();
    int below = 0;
    #pragma unroll
    for (int w = 0; w < 8; ++w) if (w < wid) below += wsum[w];
    int T = (x - s) + below;
    if (T < kk && kk <= T + s) {
        int kl = kk - T, cum = 0;
        #pragma unroll
        for (int j = 0; j < PER; ++j) {
            if (cum + v[j] >= kl) { *s_bin = base + j; *s_kk = kl - cum; break; }
            cum += v[j];
        }
    }
    __syncthreads();
}

// Merged matcher (R10-verified).
__global__ void k_match(const float* __restrict__ priors,
                        const float* __restrict__ gt_boxes,
                        const int* __restrict__ gt_labels,
                        unsigned long long* __restrict__ best_key,
                        float* __restrict__ bt_ov,
                        int* __restrict__ bt_ix,
                        int* __restrict__ bt_lab) {
    const int bid = blockIdx.x;
    if (bid < BP_BLK) {
        int pair = bid >> 2, qtr = bid & 3;
        int b = pair >> 5, o = pair & 31;
        float4 t = ((const float4*)gt_boxes)[b * O_ + o];
        float bestv = -1.0f; int besti = 0;
        int pstart = qtr * PQ;
        for (int p = pstart + threadIdx.x; p < pstart + PQ; p += 256) {
            float4 pr = ((const float4*)priors)[p];
            float v = iou_gt_prior(t, pr);
            if (v > bestv) { bestv = v; besti = p; }
        }
        __shared__ float sv[256];
        __shared__ int   si[256];
        sv[threadIdx.x] = bestv; si[threadIdx.x] = besti;
        __syncthreads();
        for (int s = 128; s > 0; s >>= 1) {
            if (threadIdx.x < s) {
                float ov = sv[threadIdx.x + s]; int oi = si[threadIdx.x + s];
                if (ov > sv[threadIdx.x] ||
                    (ov == sv[threadIdx.x] && oi < si[threadIdx.x])) {
                    sv[threadIdx.x] = ov; si[threadIdx.x] = oi;
                }
            }
            __syncthreads();
        }
        if (threadIdx.x == 0) {
            unsigned long long key =
                ((unsigned long long)__float_as_uint(sv[0]) << 32) |
                (unsigned long long)(0xFFFFFFFFu - (unsigned int)si[0]);
            atomicMax(&best_key[pair], key);
        }
    } else {
        int idx = bid - BP_BLK;
        int b = idx / BT_BPB;
        int p = (idx % BT_BPB) * 256 + threadIdx.x;
        __shared__ float4 gt[O_];
        __shared__ int    gl[O_];
        if (threadIdx.x < O_) {
            gt[threadIdx.x] = ((const float4*)gt_boxes)[b * O_ + threadIdx.x];
            gl[threadIdx.x] = gt_labels[b * O_ + threadIdx.x];
        }
        __syncthreads();
        if (p >= P_) return;
        float4 pr = ((const float4*)priors)[p];
        float bestv = -1.0f; int besti = 0;
        for (int o = 0; o < O_; ++o) {
            float v = iou_gt_prior(gt[o], pr);
            if (v > bestv) { bestv = v; besti = o; }
        }
        size_t bp = (size_t)b * P_ + p;
        bt_ov[bp] = bestv;
        bt_ix[bp] = besti;
        bt_lab[bp] = gl[besti];
    }
}

// Force-match (numpy last-wins scatter) + zero downstream accumulators.
__global__ void k_force(const unsigned long long* __restrict__ best_key,
                        const int* __restrict__ gt_labels,
                        float* __restrict__ bt_ov,
                        int* __restrict__ bt_ix,
                        int* __restrict__ bt_lab,
                        int* __restrict__ num_pos,
                        float* __restrict__ accum,
                        int* __restrict__ done) {
    const int tid = threadIdx.x;          // 512 = 16 batches x 32 gts
    const int b = tid >> 5, o = tid & 31;
    unsigned long long key = best_key[b * O_ + o];
    int p  = (int)(0xFFFFFFFFu - (unsigned int)(key & 0xFFFFFFFFu));
    int ll = gt_labels[b * O_ + o];
    if (tid < B_) num_pos[tid] = 0;
    if (tid == 0) { accum[0] = 0.0f; accum[1] = 0.0f; *done = 0; }
    const int lanebase = tid & 32;        // batch's base lane within the wave
    for (int oo = 0; oo < O_; ++oo) {
        int pp = __shfl(p, lanebase + oo);
        int l2 = __shfl(ll, lanebase + oo);
        if (o == 0) {
            size_t idx = (size_t)b * P_ + pp;
            bt_ov[idx] = 2.0f;
            bt_ix[idx] = oo;
            bt_lab[idx] = l2;
        }
    }
}

// Main pass (R6/R10 structure) with async global->LDS staging:
// __builtin_amdgcn_global_load_lds width=16 removes the VMEM->VGPR->LDS
// round-trip (no staged registers, no ds_write instructions); the barrier
// drains vmcnt once per block. LDS layout is linear: lane l of wave w lands
// at float4 slot k*512 + w*64 + l == its global slot. (Guide §5 / mistake #1.)
__global__ __launch_bounds__(TPB, 6) void
k_main(const float* __restrict__ loc_data,
       const float* __restrict__ conf_data,
       const float* __restrict__ priors,
       const float* __restrict__ gt_boxes,
       const float* __restrict__ bt_ov,
       const int* __restrict__ bt_ix,
       const int* __restrict__ bt_lab,
       float* __restrict__ lossc,
       float* __restrict__ ce_neg,
       int* __restrict__ num_pos,
       float* __restrict__ accum) {
    __shared__ float srow[RPB * C_];      // 41472 B
    __shared__ float s_lB, s_ceP;
    __shared__ int s_np0, s_np1;
    const int row0 = blockIdx.x * RPB;
    const int tid = threadIdx.x;
    const int w = tid >> 6;
    if (tid == 0) { s_lB = 0.0f; s_ceP = 0.0f; s_np0 = 0; s_np1 = 0; }

    {   // async stage: 2592 float4 = 5 full rounds + 32-lane tail
        const float4* src = (const float4*)(conf_data + (size_t)row0 * C_);
        float4* dst4 = (float4*)srow;
        #pragma unroll
        for (int k = 0; k < 5; ++k) {
            __builtin_amdgcn_global_load_lds(
                (const __attribute__((address_space(1))) void*)(src + k * 512 + tid),
                (__attribute__((address_space(3))) void*)(dst4 + k * 512 + (w << 6)),
                16, 0, 0);
        }
        if (tid < 32) {
            __builtin_amdgcn_global_load_lds(
                (const __attribute__((address_space(1))) void*)(src + 2560 + tid),
                (__attribute__((address_space(3))) void*)(dst4 + 2560),
                16, 0, 0);
        }
    }
    __syncthreads();

    const int r = tid >> 2;               // row within tile
    const int q = tid & 3;                // sub-row worker
    const int bp = row0 + r;
    const int b = bp / P_;
    const int b0 = row0 / P_;
    const int p = bp - b * P_;
    const float* row = srow + r * C_;
    const int j0 = 20 * q;

    float ma = row[j0], mb = row[j0 + 1], mc = row[j0 + 2], md = row[j0 + 3];
    #pragma unroll
    for (int i = 4; i < 20; i += 4) {
        ma = fmaxf(ma, row[j0 + i]);     mb = fmaxf(mb, row[j0 + i + 1]);
        mc = fmaxf(mc, row[j0 + i + 2]); md = fmaxf(md, row[j0 + i + 3]);
    }
    float m = fmaxf(fmaxf(ma, mb), fmaxf(mc, md));
    if (q == 3) m = fmaxf(m, row[80]);
    m = fmaxf(m, __shfl_xor(m, 1));
    m = fmaxf(m, __shfl_xor(m, 2));

    float sa = 0.f, sb = 0.f, sc = 0.f, sd = 0.f;
    #pragma unroll
    for (int i = 0; i < 20; i += 4) {
        sa += __expf(row[j0 + i] - m);     sb += __expf(row[j0 + i + 1] - m);
        sc += __expf(row[j0 + i + 2] - m); sd += __expf(row[j0 + i + 3] - m);
    }
    float s = (sa + sb) + (sc + sd);
    if (q == 3) s += __expf(row[80] - m);
    s += __shfl_xor(s, 1);
    s += __shfl_xor(s, 2);
    float logZ = m + __logf(s);

    if (q == 0) {
        float ov = bt_ov[bp];
        int lab = bt_lab[bp];
        int conf_t = lab + 1;
        if (ov < POS_TH) conf_t = -1;
        if (ov < NEG_TH) conf_t = 0;
        bool pos = conf_t > 0;

        float lc = (pos || conf_t < 0) ? 0.0f : (logZ - row[0]);
        int cls = pos ? conf_t : 0;
        float ce = logZ - row[cls];

        lossc[bp] = lc;
        ce_neg[bp] = (conf_t == 0) ? ce : 0.0f;

        if (pos) {
            int ti = bt_ix[bp];
            float4 t = ((const float4*)gt_boxes)[b * O_ + ti];
            float4 pr = ((const float4*)priors)[p];
            float mcx = (t.x + t.z) * 0.5f;
            float mcy = (t.y + t.w) * 0.5f;
            float gx = (mcx - pr.x) / (0.1f * pr.z);
            float gy = (mcy - pr.y) / (0.1f * pr.w);
            float gw = logf((t.z - t.x) / pr.z) / 0.2f;
            float gh = logf((t.w - t.y) / pr.w) / 0.2f;
            float4 ld = ((const float4*)loc_data)[bp];
            float sc2 = sl1(ld.x - gx) + sl1(ld.y - gy) + sl1(ld.z - gw) + sl1(ld.w - gh);
            atomicAdd(&s_lB, sc2);
            atomicAdd(&s_ceP, ce);
            if (b == b0) atomicAdd(&s_np0, 1); else atomicAdd(&s_np1, 1);
        }
    }
    __syncthreads();
    if (tid == 0) {
        if (s_lB != 0.0f) atomicAdd(&accum[0], s_lB);
        if (s_ceP != 0.0f) atomicAdd(&accum[1], s_ceP);
        if (s_np0) atomicAdd(&num_pos[b0], s_np0);
        if (s_np1) atomicAdd(&num_pos[b0 + 1], s_np1);   // tile spans <=2 batches
    }
}

// One block per batch: register-cached radix select (exact stable-argsort
// semantics); last block folds the final scalars and writes out[2].
__global__ __launch_bounds__(512) void
k_ohem(const float* __restrict__ lossc, const float* __restrict__ ce_neg,
       const int* __restrict__ num_pos, const float* __restrict__ accum,
       float* __restrict__ ce_sum, int* __restrict__ done,
       float* __restrict__ out) {
    const int b = blockIdx.x;
    const int tid = threadIdx.x;
    const float* lc = lossc + (size_t)b * P_;
    const float* cn = ce_neg + (size_t)b * P_;
    __shared__ int h[2048];
    __shared__ int wsum[8];
    __shared__ int s_bin, s_kk;
    __shared__ float red[512];

    int k = 3 * num_pos[b];
    if (k > P_ - 1) k = P_ - 1;

    float result = 0.0f;
    if (k > 0) {
        unsigned int fb[NJ]; float cv[NJ];
        #pragma unroll
        for (int j = 0; j < NJ; ++j) {
            int i = tid + j * 512;
            bool valid = (i < P_);
            fb[j] = valid ? __float_as_uint(lc[i]) : 0xFFFFFFFFu;
            cv[j] = valid ? cn[i] : 0.0f;
        }
        // round 0: 1024-bin hist of fb>>21 (monotone, lossc >= 0)
        for (int i = tid; i < 2048; i += 512) h[i] = 0;
        __syncthreads();
        #pragma unroll
        for (int j = 0; j < NJ; ++j) atomicAdd(&h[fb[j] >> 21], 1);
        __syncthreads();
        pick_top<2>(h, k, tid, &s_bin, &s_kk, wsum);
        const unsigned int T = (unsigned int)s_bin;
        int kk = s_kk;

        // pass A: sum ce for bins > T; hist bits 20..10 of bin==T
        for (int i = tid; i < 2048; i += 512) h[i] = 0;
        __syncthreads();
        float sum = 0.0f;
        #pragma unroll
        for (int j = 0; j < NJ; ++j) {
            unsigned int bin = fb[j] >> 21;
            if (bin > T) sum += cv[j];                 // sentinel adds 0
            else if (bin == T) atomicAdd(&h[(fb[j] >> 10) & 2047], 1);
        }
        __syncthreads();
        pick_top<4>(h, kk, tid, &s_bin, &s_kk, wsum);
        const unsigned int pre21 = (T << 11) | (unsigned int)s_bin;
        kk = s_kk;

        // pass B: hist bits 9..0 of elements matching top 22 bits
        for (int i = tid; i < 1024; i += 512) h[i] = 0;
        __syncthreads();
        #pragma unroll
        for (int j = 0; j < NJ; ++j)
            if ((fb[j] >> 10) == pre21) atomicAdd(&h[fb[j] & 1023], 1);
        __syncthreads();
        pick_top<2>(h, kk, tid, &s_bin, &s_kk, wsum);
        const unsigned int V = (pre21 << 10) | (unsigned int)s_bin;
        const int ee = h[s_bin];
        kk = s_kk;

        if (kk == ee) {
            #pragma unroll
            for (int j = 0; j < NJ; ++j)
                if ((fb[j] >> 21) == T && fb[j] >= V) sum += cv[j];
        } else {
            // kk smallest-index elements with fb == V (stable argsort ties)
            for (int i = tid; i < 512; i += 512) h[i] = 0;
            __syncthreads();
            #pragma unroll
            for (int j = 0; j < NJ; ++j)
                if (fb[j] == V) atomicAdd(&h[(tid + j * 512) >> 6], 1);
            __syncthreads();
            pick_bot<1>(h, kk, tid, &s_bin, &s_kk, wsum);
            const int d6 = s_bin;
            kk = s_kk;
            h[tid] = 0;
            __syncthreads();
            #pragma unroll
            for (int j = 0; j < NJ; ++j) {
                int i = tid + j * 512;
                if (fb[j] == V && (i >> 6) == d6) atomicAdd(&h[i & 63], 1);
            }
            __syncthreads();
            pick_bot<1>(h, kk, tid, &s_bin, &s_kk, wsum);
            const int Istar = (d6 << 6) | s_bin;
            #pragma unroll
            for (int j = 0; j < NJ; ++j) {
                int i = tid + j * 512;
                if ((fb[j] >> 21) == T && (fb[j] > V || (fb[j] == V && i <= Istar)))
                    sum += cv[j];
            }
        }

        red[tid] = sum;
        __syncthreads();
        for (int s = 256; s > 0; s >>= 1) {
            if (tid < s) red[tid] += red[tid + s];
            __syncthreads();
        }
        result = red[0];
    }

    if (tid == 0) {
        ce_sum[b] = result;
        __threadfence();
        int old = atomicAdd(done, 1);
        if (old == B_ - 1) {                  // last block folds the output
            __threadfence();
            int tp = 0; float ns = 0.0f;
            for (int bb = 0; bb < B_; ++bb) { tp += num_pos[bb]; ns += ce_sum[bb]; }
            float inv = 1.0f / (float)tp;
            out[0] = accum[0] * 1.5f * inv;   // BBOX_ALPHA
            out[1] = (accum[1] + ns) * inv;   // CONF_ALPHA
        }
    }
}

extern "C" void kernel_launch(void* const* d_in, const int* in_sizes, int n_in,
                              void* d_out, int out_size, void* d_ws, size_t ws_size,
                              hipStream_t stream) {
    const float* loc    = (const float*)d_in[0];
    const float* conf   = (const float*)d_in[1];
    const float* priors = (const float*)d_in[2];
    const float* gtb    = (const float*)d_in[3];
    const int*   gtl    = (const int*)d_in[4];
    float* out = (float*)d_out;

    const size_t BP = (size_t)B_ * P_;
    float* W = (float*)d_ws;
    float* bt_ov   = W;
    float* lossc   = W + BP;
    float* ce_neg  = W + 2 * BP;
    int*   bt_ix   = (int*)(W + 3 * BP);
    int*   bt_lab  = (int*)(W + 4 * BP);
    unsigned long long* best_key = (unsigned long long*)(W + 5 * BP);  // 8B-aligned
    int*   num_pos = (int*)(best_key + B_ * O_);
    float* ce_sum  = (float*)(num_pos + B_);
    float* accum   = ce_sum + B_;
    int*   done    = (int*)(accum + 2);

    hipMemsetAsync(best_key, 0, B_ * O_ * sizeof(unsigned long long), stream);
    hipLaunchKernelGGL(k_match, dim3(BP_BLK + B_ * BT_BPB), dim3(256), 0, stream,
                       priors, gtb, gtl, best_key, bt_ov, bt_ix, bt_lab);
    hipLaunchKernelGGL(k_force, dim3(1), dim3(512), 0, stream,
                       best_key, gtl, bt_ov, bt_ix, bt_lab, num_pos, accum, done);
    hipLaunchKernelGGL(k_main, dim3((int)(BP / RPB)), dim3(TPB), 0, stream,
                       loc, conf, priors, gtb, bt_ov, bt_ix, bt_lab,
                       lossc, ce_neg, num_pos, accum);
    hipLaunchKernelGGL(k_ohem, dim3(B_), dim3(512), 0, stream,
                       lossc, ce_neg, num_pos, accum, ce_sum, done, out);
}

// Round 14
// 118.963 us; speedup vs baseline: 1.8011x; 1.0082x over previous
//
#include <hip/hip_runtime.h>
#include <math.h>

#define B_ 16
#define P_ 19248
#define C_ 81
#define O_ 32
#define POS_TH 0.5f
#define NEG_TH 0.4f
#define RPB 128              // rows per k_main tile; B_*P_ = 307968 = 2406*128
#define TPB 512              // threads per k_main block (8 waves), 4 threads/row
#define PQ  4812             // P_/4: priors per best_prior quarter-block
#define BP_BLK (B_ * O_ * 4) // 2048 best_prior quarter blocks
#define BT_BPB 76            // ceil(P_/256) best_truth blocks per batch
#define OT 1024              // k_ohem threads (16 waves)
#define NJ 19                // ceil(P_/OT) per-thread elements in k_ohem

__device__ __forceinline__ float sl1(float x) {
    float d = fabsf(x);
    return (d < 1.0f) ? 0.5f * d * d : d - 0.5f;
}

__device__ __forceinline__ float iou_gt_prior(float4 t, float4 pr) {
    float px1 = pr.x - pr.z * 0.5f;
    float py1 = pr.y - pr.w * 0.5f;
    float px2 = pr.x + pr.z * 0.5f;
    float py2 = pr.y + pr.w * 0.5f;
    float ltx = fmaxf(t.x, px1), lty = fmaxf(t.y, py1);
    float rbx = fminf(t.z, px2), rby = fminf(t.w, py2);
    float iw = fmaxf(rbx - ltx, 0.0f), ih = fmaxf(rby - lty, 0.0f);
    float inter = iw * ih;
    float area_t = (t.z - t.x) * (t.w - t.y);
    float area_p = (px2 - px1) * (py2 - py1);
    return inter / (area_t + area_p - inter);
}

// ---- parallel threshold picks for OT=1024 threads (16 waves) ----
// h[] must be fully sized/zeroed to OT*PER bins; zero bins are neutral.
template <int PER>
__device__ __forceinline__ void pick_top(const int* __restrict__ h, int kk, int tid,
                                         int* s_bin, int* s_kk, int* wsum) {
    const int lane = tid & 63, wid = tid >> 6;
    const int base = tid * PER;
    int v[PER]; int s = 0;
    #pragma unroll
    for (int j = 0; j < PER; ++j) { v[j] = h[base + j]; s += v[j]; }
    int x = s;                                  // inclusive suffix scan in wave
    #pragma unroll
    for (int d = 1; d < 64; d <<= 1) {
        int y = __shfl_down(x, d);
        if (lane + d < 64) x += y;
    }
    if (lane == 0) wsum[wid] = x;
    __syncthreads();
    int above = 0;
    #pragma unroll
    for (int w = 0; w < 16; ++w) if (w > wid) above += wsum[w];
    int T = (x - s) + above;
    if (T < kk && kk <= T + s) {                // exactly one thread true
        int kl = kk - T, cum = 0;
        #pragma unroll
        for (int j = PER - 1; j >= 0; --j) {
            if (cum + v[j] >= kl) { *s_bin = base + j; *s_kk = kl - cum; break; }
            cum += v[j];
        }
    }
    __syncthreads();
}

template <int PER>
__device__ __forceinline__ void pick_bot(const int* __restrict__ h, int kk, int tid,
                                         int* s_bin, int* s_kk, int* wsum) {
    const int lane = tid & 63, wid = tid >> 6;
    const int base = tid * PER;
    int v[PER]; int s = 0;
    #pragma unroll
    for (int j = 0; j < PER; ++j) { v[j] = h[base + j]; s += v[j]; }
    int x = s;                                  // inclusive prefix scan in wave
    #pragma unroll
    for (int d = 1; d < 64; d <<= 1) {
        int y = __shfl_up(x, d);
        if (lane >= d) x += y;
    }
    if (lane == 63) wsum[wid] = x;
    __syncthreads();
    int below = 0;
    #pragma unroll
    for (int w = 0; w < 16; ++w) if (w < wid) below += wsum[w];
    int T = (x - s) + below;
    if (T < kk && kk <= T + s) {
        int kl = kk - T, cum = 0;
        #pragma unroll
        for (int j = 0; j < PER; ++j) {
            if (cum + v[j] >= kl) { *s_bin = base + j; *s_kk = kl - cum; break; }
            cum += v[j];
        }
    }
    __syncthreads();
}

// Merged matcher (R12-verified; pure matcher, no cross-block write hazards).
__global__ void k_match(const float* __restrict__ priors,
                        const float* __restrict__ gt_boxes,
                        const int* __restrict__ gt_labels,
                        unsigned long long* __restrict__ best_key,
                        float* __restrict__ bt_ov,
                        int* __restrict__ bt_ix,
                        int* __restrict__ bt_lab) {
    const int bid = blockIdx.x;
    if (bid < BP_BLK) {
        int pair = bid >> 2, qtr = bid & 3;
        int b = pair >> 5, o = pair & 31;
        float4 t = ((const float4*)gt_boxes)[b * O_ + o];
        float bestv = -1.0f; int besti = 0;
        int pstart = qtr * PQ;
        for (int p = pstart + threadIdx.x; p < pstart + PQ; p += 256) {
            float4 pr = ((const float4*)priors)[p];
            float v = iou_gt_prior(t, pr);
            if (v > bestv) { bestv = v; besti = p; }
        }
        __shared__ float sv[256];
        __shared__ int   si[256];
        sv[threadIdx.x] = bestv; si[threadIdx.x] = besti;
        __syncthreads();
        for (int s = 128; s > 0; s >>= 1) {
            if (threadIdx.x < s) {
                float ov = sv[threadIdx.x + s]; int oi = si[threadIdx.x + s];
                if (ov > sv[threadIdx.x] ||
                    (ov == sv[threadIdx.x] && oi < si[threadIdx.x])) {
                    sv[threadIdx.x] = ov; si[threadIdx.x] = oi;
                }
            }
            __syncthreads();
        }
        if (threadIdx.x == 0) {
            unsigned long long key =
                ((unsigned long long)__float_as_uint(sv[0]) << 32) |
                (unsigned long long)(0xFFFFFFFFu - (unsigned int)si[0]);
            atomicMax(&best_key[pair], key);
        }
    } else {
        int idx = bid - BP_BLK;
        int b = idx / BT_BPB;
        int p = (idx % BT_BPB) * 256 + threadIdx.x;
        __shared__ float4 gt[O_];
        __shared__ int    gl[O_];
        if (threadIdx.x < O_) {
            gt[threadIdx.x] = ((const float4*)gt_boxes)[b * O_ + threadIdx.x];
            gl[threadIdx.x] = gt_labels[b * O_ + threadIdx.x];
        }
        __syncthreads();
        if (p >= P_) return;
        float4 pr = ((const float4*)priors)[p];
        float bestv = -1.0f; int besti = 0;
        for (int o = 0; o < O_; ++o) {
            float v = iou_gt_prior(gt[o], pr);
            if (v > bestv) { bestv = v; besti = o; }
        }
        size_t bp = (size_t)b * P_ + p;
        bt_ov[bp] = bestv;
        bt_ix[bp] = besti;
        bt_lab[bp] = gl[besti];
    }
}

// Main pass (R6/R12-verified, 76us): async global->LDS staging, 4 thr/row
// logsumexp. Force-match applied FUNCTIONALLY here: each block stages its
// <=2 batches' 32 best_key entries into LDS; each row checks p against the
// forced priors (scan oo=31->0, first hit = numpy last-wins). No cross-
// kernel scatter, so no XCD dirty-line hazard (R13's bug).
__global__ __launch_bounds__(TPB, 6) void
k_main(const float* __restrict__ loc_data,
       const float* __restrict__ conf_data,
       const float* __restrict__ priors,
       const float* __restrict__ gt_boxes,
       const int* __restrict__ gt_labels,
       const unsigned long long* __restrict__ best_key,
       const float* __restrict__ bt_ov,
       const int* __restrict__ bt_ix,
       const int* __restrict__ bt_lab,
       float* __restrict__ lossc,
       float* __restrict__ ce_neg,
       int* __restrict__ num_pos,
       float* __restrict__ accum) {
    __shared__ float srow[RPB * C_];      // 41472 B
    __shared__ int s_fp[2][O_];           // forced prior per (batch-half, o)
    __shared__ int s_fl[2][O_];           // its label
    __shared__ float s_lB, s_ceP;
    __shared__ int s_np0, s_np1;
    const int row0 = blockIdx.x * RPB;
    const int b0 = row0 / P_;
    const int tid = threadIdx.x;
    const int w = tid >> 6;
    if (tid == 0) { s_lB = 0.0f; s_ceP = 0.0f; s_np0 = 0; s_np1 = 0; }

    {   // async stage: 2592 float4 = 5 full rounds + 32-lane tail
        const float4* src = (const float4*)(conf_data + (size_t)row0 * C_);
        float4* dst4 = (float4*)srow;
        #pragma unroll
        for (int k = 0; k < 5; ++k) {
            __builtin_amdgcn_global_load_lds(
                (const __attribute__((address_space(1))) void*)(src + k * 512 + tid),
                (__attribute__((address_space(3))) void*)(dst4 + k * 512 + (w << 6)),
                16, 0, 0);
        }
        if (tid < 32) {
            __builtin_amdgcn_global_load_lds(
                (const __attribute__((address_space(1))) void*)(src + 2560 + tid),
                (__attribute__((address_space(3))) void*)(dst4 + 2560),
                16, 0, 0);
        }
    }
    // stage force-match table for this block's <=2 batches
    if (tid < 2 * O_) {
        int half = tid >> 5, o = tid & 31;
        int bb = b0 + half;
        int fp = -1, fl = 0;
        if (bb < B_) {
            unsigned long long key = best_key[bb * O_ + o];
            fp = (int)(0xFFFFFFFFu - (unsigned int)(key & 0xFFFFFFFFu));
            fl = gt_labels[bb * O_ + o];
        }
        s_fp[half][o] = fp;
        s_fl[half][o] = fl;
    }
    __syncthreads();

    const int r = tid >> 2;               // row within tile
    const int q = tid & 3;                // sub-row worker
    const int bp = row0 + r;
    const int b = bp / P_;
    const int p = bp - b * P_;
    const float* row = srow + r * C_;
    const int j0 = 20 * q;

    float ma = row[j0], mb = row[j0 + 1], mc = row[j0 + 2], md = row[j0 + 3];
    #pragma unroll
    for (int i = 4; i < 20; i += 4) {
        ma = fmaxf(ma, row[j0 + i]);     mb = fmaxf(mb, row[j0 + i + 1]);
        mc = fmaxf(mc, row[j0 + i + 2]); md = fmaxf(md, row[j0 + i + 3]);
    }
    float m = fmaxf(fmaxf(ma, mb), fmaxf(mc, md));
    if (q == 3) m = fmaxf(m, row[80]);
    m = fmaxf(m, __shfl_xor(m, 1));
    m = fmaxf(m, __shfl_xor(m, 2));

    float sa = 0.f, sb = 0.f, sc = 0.f, sd = 0.f;
    #pragma unroll
    for (int i = 0; i < 20; i += 4) {
        sa += __expf(row[j0 + i] - m);     sb += __expf(row[j0 + i + 1] - m);
        sc += __expf(row[j0 + i + 2] - m); sd += __expf(row[j0 + i + 3] - m);
    }
    float s = (sa + sb) + (sc + sd);
    if (q == 3) s += __expf(row[80] - m);
    s += __shfl_xor(s, 1);
    s += __shfl_xor(s, 2);
    float logZ = m + __logf(s);

    if (q == 0) {
        // force-match check: scan oo=31..0, first hit = last-wins
        const int whichb = b - b0;
        int foo = -1;
        #pragma unroll
        for (int oo = O_ - 1; oo >= 0; --oo) {
            if (foo < 0 && s_fp[whichb][oo] == p) foo = oo;
        }
        int conf_t, ti = 0;
        bool pos;
        if (foo >= 0) {                   // forced: ov=2.0 -> positive
            conf_t = s_fl[whichb][foo] + 1;
            pos = true;
            ti = foo;
        } else {
            float ov = bt_ov[bp];
            conf_t = bt_lab[bp] + 1;
            if (ov < POS_TH) conf_t = -1;
            if (ov < NEG_TH) conf_t = 0;
            pos = conf_t > 0;
            if (pos) ti = bt_ix[bp];
        }

        float lc = (pos || conf_t < 0) ? 0.0f : (logZ - row[0]);
        int cls = pos ? conf_t : 0;
        float ce = logZ - row[cls];

        lossc[bp] = lc;
        ce_neg[bp] = (conf_t == 0) ? ce : 0.0f;

        if (pos) {
            float4 t = ((const float4*)gt_boxes)[b * O_ + ti];
            float4 pr = ((const float4*)priors)[p];
            float mcx = (t.x + t.z) * 0.5f;
            float mcy = (t.y + t.w) * 0.5f;
            float gx = (mcx - pr.x) / (0.1f * pr.z);
            float gy = (mcy - pr.y) / (0.1f * pr.w);
            float gw = logf((t.z - t.x) / pr.z) / 0.2f;
            float gh = logf((t.w - t.y) / pr.w) / 0.2f;
            float4 ld = ((const float4*)loc_data)[bp];
            float sc2 = sl1(ld.x - gx) + sl1(ld.y - gy) + sl1(ld.z - gw) + sl1(ld.w - gh);
            atomicAdd(&s_lB, sc2);
            atomicAdd(&s_ceP, ce);
            if (b == b0) atomicAdd(&s_np0, 1); else atomicAdd(&s_np1, 1);
        }
    }
    __syncthreads();
    if (tid == 0) {
        if (s_lB != 0.0f) atomicAdd(&accum[0], s_lB);
        if (s_ceP != 0.0f) atomicAdd(&accum[1], s_ceP);
        if (s_np0) atomicAdd(&num_pos[b0], s_np0);
        if (s_np1) atomicAdd(&num_pos[b0 + 1], s_np1);   // tile spans <=2 batches
    }
}

// One block per batch, 1024 threads: register-cached radix select (exact
// stable-argsort semantics). Sentinels (i >= P_) use fb=0, cv=0: they rank
// strictly below every real element (value 0, largest indices), so with
// k <= P_-1 they never shift the threshold and contribute 0 to sums.
// (R13's bug: fb=0xFFFFFFFF sentinels landed in scanned bin 2047.)
__global__ __launch_bounds__(OT) void
k_ohem(const float* __restrict__ lossc, const float* __restrict__ ce_neg,
       const int* __restrict__ num_pos, const float* __restrict__ accum,
       float* __restrict__ ce_sum, int* __restrict__ done,
       float* __restrict__ out) {
    const int b = blockIdx.x;
    const int tid = threadIdx.x;
    const float* lc = lossc + (size_t)b * P_;
    const float* cn = ce_neg + (size_t)b * P_;
    __shared__ int h[2048];
    __shared__ int wsum[16];
    __shared__ int s_bin, s_kk;
    __shared__ float red[OT];

    int k = 3 * num_pos[b];
    if (k > P_ - 1) k = P_ - 1;

    float result = 0.0f;
    if (k > 0) {
        unsigned int fb[NJ]; float cv[NJ];
        #pragma unroll
        for (int j = 0; j < NJ; ++j) {
            int i = tid + j * OT;
            bool valid = (i < P_);
            fb[j] = valid ? __float_as_uint(lc[i]) : 0u;   // bottom-ranked sentinel
            cv[j] = valid ? cn[i] : 0.0f;
        }
        // round 0: 1024-bin hist of fb>>21 (monotone, lossc >= 0)
        h[tid] = 0; h[tid + 1024] = 0;
        __syncthreads();
        #pragma unroll
        for (int j = 0; j < NJ; ++j) atomicAdd(&h[fb[j] >> 21], 1);
        __syncthreads();
        pick_top<2>(h, k, tid, &s_bin, &s_kk, wsum);
        const unsigned int T = (unsigned int)s_bin;
        int kk = s_kk;

        // pass A: sum ce for bins > T; hist bits 20..10 of bin==T
        h[tid] = 0; h[tid + 1024] = 0;
        __syncthreads();
        float sum = 0.0f;
        #pragma unroll
        for (int j = 0; j < NJ; ++j) {
            unsigned int bin = fb[j] >> 21;
            if (bin > T) sum += cv[j];
            else if (bin == T) atomicAdd(&h[(fb[j] >> 10) & 2047], 1);
        }
        __syncthreads();
        pick_top<2>(h, kk, tid, &s_bin, &s_kk, wsum);
        const unsigned int pre21 = (T << 11) | (unsigned int)s_bin;
        kk = s_kk;

        // pass B: hist bits 9..0 of elements matching top 22 bits
        h[tid] = 0; h[tid + 1024] = 0;
        __syncthreads();
        #pragma unroll
        for (int j = 0; j < NJ; ++j)
            if ((fb[j] >> 10) == pre21) atomicAdd(&h[fb[j] & 1023], 1);
        __syncthreads();
        pick_top<2>(h, kk, tid, &s_bin, &s_kk, wsum);
        const unsigned int V = (pre21 << 10) | (unsigned int)s_bin;
        const int ee = h[s_bin];
        kk = s_kk;

        if (kk == ee) {
            #pragma unroll
            for (int j = 0; j < NJ; ++j)
                if ((fb[j] >> 21) == T && fb[j] >= V) sum += cv[j];
        } else {
            // kk smallest-index elements with fb == V (stable argsort ties);
            // sentinels at fb==0==V lose by index and carry cv=0.
            h[tid] = 0; h[tid + 1024] = 0;
            __syncthreads();
            #pragma unroll
            for (int j = 0; j < NJ; ++j)
                if (fb[j] == V) atomicAdd(&h[(tid + j * OT) >> 6], 1);
            __syncthreads();
            pick_bot<2>(h, kk, tid, &s_bin, &s_kk, wsum);
            const int d6 = s_bin;
            kk = s_kk;
            h[tid] = 0; h[tid + 1024] = 0;
            __syncthreads();
            #pragma unroll
            for (int j = 0; j < NJ; ++j) {
                int i = tid + j * OT;
                if (fb[j] == V && (i >> 6) == d6) atomicAdd(&h[i & 63], 1);
            }
            __syncthreads();
            pick_bot<2>(h, kk, tid, &s_bin, &s_kk, wsum);
            const int Istar = (d6 << 6) | s_bin;
            #pragma unroll
            for (int j = 0; j < NJ; ++j) {
                int i = tid + j * OT;
                if ((fb[j] >> 21) == T && (fb[j] > V || (fb[j] == V && i <= Istar)))
                    sum += cv[j];
            }
        }

        red[tid] = sum;
        __syncthreads();
        for (int s = OT / 2; s > 0; s >>= 1) {
            if (tid < s) red[tid] += red[tid + s];
            __syncthreads();
        }
        result = red[0];
    }

    if (tid == 0) {
        ce_sum[b] = result;
        __threadfence();
        int old = atomicAdd(done, 1);
        if (old == B_ - 1) {                  // last block folds the output
            __threadfence();
            int tp = 0; float ns = 0.0f;
            for (int bb = 0; bb < B_; ++bb) { tp += num_pos[bb]; ns += ce_sum[bb]; }
            float inv = 1.0f / (float)tp;
            out[0] = accum[0] * 1.5f * inv;   // BBOX_ALPHA
            out[1] = (accum[1] + ns) * inv;   // CONF_ALPHA
        }
    }
}

extern "C" void kernel_launch(void* const* d_in, const int* in_sizes, int n_in,
                              void* d_out, int out_size, void* d_ws, size_t ws_size,
                              hipStream_t stream) {
    const float* loc    = (const float*)d_in[0];
    const float* conf   = (const float*)d_in[1];
    const float* priors = (const float*)d_in[2];
    const float* gtb    = (const float*)d_in[3];
    const int*   gtl    = (const int*)d_in[4];
    float* out = (float*)d_out;

    const size_t BP = (size_t)B_ * P_;
    float* W = (float*)d_ws;
    float* bt_ov   = W;
    float* lossc   = W + BP;
    float* ce_neg  = W + 2 * BP;
    int*   bt_ix   = (int*)(W + 3 * BP);
    int*   bt_lab  = (int*)(W + 4 * BP);
    unsigned long long* best_key = (unsigned long long*)(W + 5 * BP);  // 8B-aligned
    int*   num_pos = (int*)(best_key + B_ * O_);
    float* ce_sum  = (float*)(num_pos + B_);
    float* accum   = ce_sum + B_;
    int*   done    = (int*)(accum + 2);

    // zero best_key + num_pos + ce_sum + accum + done in one memset
    size_t zbytes = B_ * O_ * sizeof(unsigned long long) +
                    B_ * sizeof(int) + B_ * sizeof(float) +
                    2 * sizeof(float) + sizeof(int);
    hipMemsetAsync(best_key, 0, zbytes, stream);
    hipLaunchKernelGGL(k_match, dim3(BP_BLK + B_ * BT_BPB), dim3(256), 0, stream,
                       priors, gtb, gtl, best_key, bt_ov, bt_ix, bt_lab);
    hipLaunchKernelGGL(k_main, dim3((int)(BP / RPB)), dim3(TPB), 0, stream,
                       loc, conf, priors, gtb, gtl, best_key,
                       bt_ov, bt_ix, bt_lab, lossc, ce_neg, num_pos, accum);
    hipLaunchKernelGGL(k_ohem, dim3(B_), dim3(OT), 0, stream,
                       lossc, ce_neg, num_pos, accum, ce_sum, done, out);
}